// Round 1
// baseline (493.747 us; speedup 1.0000x reference)
//
#include <hip/hip_runtime.h>
#include <math.h>

#define IN_DIM 64
#define HH 4
#define DD 32
#define CC 128   /* HH*DD */
#define NEG_SLOPE 0.1f

__device__ __forceinline__ float leaky(float v) { return v >= 0.f ? v : NEG_SLOPE * v; }

// ---------------- Kernel 1: feat = x @ W_fc ; el/er = per-head dots ----------------
__global__ __launch_bounds__(256) void k_project(
    const float* __restrict__ x, const float* __restrict__ W,
    const float* __restrict__ attn_l, const float* __restrict__ attn_r,
    float* __restrict__ feat, float* __restrict__ el, float* __restrict__ er,
    int N)
{
  __shared__ float Wl[IN_DIM * CC];
  __shared__ float Al[CC];
  __shared__ float Ar[CC];
  int t = threadIdx.x;
  for (int i = t; i < IN_DIM * CC / 4; i += 256)
    reinterpret_cast<float4*>(Wl)[i] = reinterpret_cast<const float4*>(W)[i];
  if (t < CC) { Al[t] = attn_l[t]; Ar[t] = attn_r[t]; }
  __syncthreads();

  int lane = t & 63;
  int row = blockIdx.x * 4 + (t >> 6);
  if (row >= N) return;

  float xv = x[row * IN_DIM + lane];           // lane k holds x[row][k]
  float acc0 = 0.f, acc1 = 0.f;                // cols 2*lane, 2*lane+1
#pragma unroll
  for (int k = 0; k < IN_DIM; ++k) {
    float xk = __shfl(xv, k, 64);
    float2 wv = *reinterpret_cast<const float2*>(&Wl[k * CC + 2 * lane]);
    acc0 = fmaf(xk, wv.x, acc0);
    acc1 = fmaf(xk, wv.y, acc1);
  }
  *reinterpret_cast<float2*>(&feat[row * CC + 2 * lane]) = make_float2(acc0, acc1);

  int c = 2 * lane;
  float pl = acc0 * Al[c] + acc1 * Al[c + 1];
  float pr = acc0 * Ar[c] + acc1 * Ar[c + 1];
#pragma unroll
  for (int m = 8; m >= 1; m >>= 1) {           // reduce within 16-lane head group
    pl += __shfl_xor(pl, m, 64);
    pr += __shfl_xor(pr, m, 64);
  }
  if ((lane & 15) == 0) {
    int h = lane >> 4;
    el[row * HH + h] = pl;
    er[row * HH + h] = pr;
  }
}

// ---------------- CSR build ----------------
__global__ void k_hist(const int* __restrict__ dst, int* __restrict__ counts, int E) {
  int i = blockIdx.x * blockDim.x + threadIdx.x;
  if (i < E) atomicAdd(&counts[dst[i]], 1);
}

// exclusive scan, 1024 elems/block (256 thr x 4)
__global__ __launch_bounds__(256) void k_scan1(int* __restrict__ data, int* __restrict__ bsum, int N) {
  __shared__ int sh[256];
  int t = threadIdx.x;
  int base = blockIdx.x * 1024 + t * 4;
  int v0 = (base + 0 < N) ? data[base + 0] : 0;
  int v1 = (base + 1 < N) ? data[base + 1] : 0;
  int v2 = (base + 2 < N) ? data[base + 2] : 0;
  int v3 = (base + 3 < N) ? data[base + 3] : 0;
  int s1 = v0 + v1, s2 = s1 + v2, s3 = s2 + v3;
  sh[t] = s3;
  __syncthreads();
  for (int off = 1; off < 256; off <<= 1) {
    int add = (t >= off) ? sh[t - off] : 0;
    __syncthreads();
    sh[t] += add;
    __syncthreads();
  }
  int incl = sh[t];
  int e0 = incl - s3;          // exclusive base for this thread
  int e1 = e0 + v0, e2 = e1 + v1, e3 = e2 + v2;
  if (base + 0 < N) data[base + 0] = e0;
  if (base + 1 < N) data[base + 1] = e1;
  if (base + 2 < N) data[base + 2] = e2;
  if (base + 3 < N) data[base + 3] = e3;
  if (t == 255) bsum[blockIdx.x] = incl;
}

__global__ __launch_bounds__(256) void k_scan2(int* __restrict__ bsum, int G) {
  __shared__ int sh[256];
  int t = threadIdx.x;
  int v = (t < G) ? bsum[t] : 0;
  sh[t] = v;
  __syncthreads();
  for (int off = 1; off < 256; off <<= 1) {
    int add = (t >= off) ? sh[t - off] : 0;
    __syncthreads();
    sh[t] += add;
    __syncthreads();
  }
  if (t < G) bsum[t] = sh[t] - v;  // exclusive
}

__global__ void k_scan3(int* __restrict__ data, const int* __restrict__ bsum, int N, int E) {
  int i = blockIdx.x * blockDim.x + threadIdx.x;
  if (i < N) data[i] += bsum[i >> 10];
  if (i == 0) data[N] = E;
}

__global__ void k_scatter(const int* __restrict__ src, const int* __restrict__ dst,
                          const float* __restrict__ w, const int* __restrict__ offs,
                          int* __restrict__ cursor, int* __restrict__ ssrc,
                          float* __restrict__ sw, int E) {
  int i = blockIdx.x * blockDim.x + threadIdx.x;
  if (i < E) {
    int d = dst[i];
    int r = atomicAdd(&cursor[d], 1);
    int pos = offs[d] + r;
    ssrc[pos] = src[i];
    sw[pos] = w[i];
  }
}

// ---------------- Kernel 3: per-node softmax + weighted gather-sum ----------------
__global__ __launch_bounds__(256) void k_aggregate(
    const int* __restrict__ offs, const int* __restrict__ ssrc,
    const float* __restrict__ sw, const float* __restrict__ el,
    const float* __restrict__ er, const float* __restrict__ feat,
    float* __restrict__ out, int N)
{
  int lane = threadIdx.x & 63;
  int n = blockIdx.x * 4 + (threadIdx.x >> 6);
  if (n >= N) return;

  int off0 = offs[n], off1 = offs[n + 1];
  int deg = off1 - off0;
  int h = lane >> 4;                       // head owning cols 2*lane, 2*lane+1
  float4 erv = *reinterpret_cast<const float4*>(&er[n * HH]);
  float acc0 = 0.f, acc1 = 0.f;

  if (deg > 0) {
    if (deg <= 64) {
      bool act = lane < deg;
      int j = off0 + (act ? lane : 0);
      int s = ssrc[j];
      float wv = sw[j];
      float4 elv = *reinterpret_cast<const float4*>(&el[s * HH]);
      float e0 = leaky(elv.x + erv.x) * wv;
      float e1 = leaky(elv.y + erv.y) * wv;
      float e2 = leaky(elv.z + erv.z) * wv;
      float e3 = leaky(elv.w + erv.w) * wv;
      if (!act) { e0 = e1 = e2 = e3 = -INFINITY; }
      float m0 = e0, m1 = e1, m2 = e2, m3 = e3;
#pragma unroll
      for (int d = 32; d >= 1; d >>= 1) {
        m0 = fmaxf(m0, __shfl_xor(m0, d, 64));
        m1 = fmaxf(m1, __shfl_xor(m1, d, 64));
        m2 = fmaxf(m2, __shfl_xor(m2, d, 64));
        m3 = fmaxf(m3, __shfl_xor(m3, d, 64));
      }
      float x0 = act ? __expf(e0 - m0) : 0.f;
      float x1 = act ? __expf(e1 - m1) : 0.f;
      float x2 = act ? __expf(e2 - m2) : 0.f;
      float x3 = act ? __expf(e3 - m3) : 0.f;
      float d0 = x0, d1 = x1, d2 = x2, d3 = x3;
#pragma unroll
      for (int d = 32; d >= 1; d >>= 1) {
        d0 += __shfl_xor(d0, d, 64);
        d1 += __shfl_xor(d1, d, 64);
        d2 += __shfl_xor(d2, d, 64);
        d3 += __shfl_xor(d3, d, 64);
      }
      float a0 = x0 / d0, a1 = x1 / d1, a2 = x2 / d2, a3 = x3 / d3;
      for (int jj = 0; jj < deg; ++jj) {
        int sj = __shfl(s, jj, 64);
        float b0 = __shfl(a0, jj, 64);
        float b1 = __shfl(a1, jj, 64);
        float b2 = __shfl(a2, jj, 64);
        float b3 = __shfl(a3, jj, 64);
        float av = h == 0 ? b0 : h == 1 ? b1 : h == 2 ? b2 : b3;
        float2 f = *reinterpret_cast<const float2*>(&feat[(size_t)sj * CC + 2 * lane]);
        acc0 = fmaf(av, f.x, acc0);
        acc1 = fmaf(av, f.y, acc1);
      }
    } else {
      // generic chunked path (deg > 64): 3 passes, recompute logits each pass
      float m0 = -INFINITY, m1 = -INFINITY, m2 = -INFINITY, m3 = -INFINITY;
      for (int base = off0; base < off1; base += 64) {
        int j = base + lane;
        bool act = j < off1;
        int jc = act ? j : off0;
        int s = ssrc[jc];
        float wv = sw[jc];
        float4 elv = *reinterpret_cast<const float4*>(&el[s * HH]);
        float e0 = leaky(elv.x + erv.x) * wv;
        float e1 = leaky(elv.y + erv.y) * wv;
        float e2 = leaky(elv.z + erv.z) * wv;
        float e3 = leaky(elv.w + erv.w) * wv;
        if (!act) { e0 = e1 = e2 = e3 = -INFINITY; }
        m0 = fmaxf(m0, e0); m1 = fmaxf(m1, e1);
        m2 = fmaxf(m2, e2); m3 = fmaxf(m3, e3);
      }
#pragma unroll
      for (int d = 32; d >= 1; d >>= 1) {
        m0 = fmaxf(m0, __shfl_xor(m0, d, 64));
        m1 = fmaxf(m1, __shfl_xor(m1, d, 64));
        m2 = fmaxf(m2, __shfl_xor(m2, d, 64));
        m3 = fmaxf(m3, __shfl_xor(m3, d, 64));
      }
      float d0 = 0.f, d1 = 0.f, d2 = 0.f, d3 = 0.f;
      for (int base = off0; base < off1; base += 64) {
        int j = base + lane;
        bool act = j < off1;
        int jc = act ? j : off0;
        int s = ssrc[jc];
        float wv = sw[jc];
        float4 elv = *reinterpret_cast<const float4*>(&el[s * HH]);
        float e0 = leaky(elv.x + erv.x) * wv;
        float e1 = leaky(elv.y + erv.y) * wv;
        float e2 = leaky(elv.z + erv.z) * wv;
        float e3 = leaky(elv.w + erv.w) * wv;
        d0 += act ? __expf(e0 - m0) : 0.f;
        d1 += act ? __expf(e1 - m1) : 0.f;
        d2 += act ? __expf(e2 - m2) : 0.f;
        d3 += act ? __expf(e3 - m3) : 0.f;
      }
#pragma unroll
      for (int d = 32; d >= 1; d >>= 1) {
        d0 += __shfl_xor(d0, d, 64);
        d1 += __shfl_xor(d1, d, 64);
        d2 += __shfl_xor(d2, d, 64);
        d3 += __shfl_xor(d3, d, 64);
      }
      float i0 = 1.f / d0, i1 = 1.f / d1, i2 = 1.f / d2, i3 = 1.f / d3;
      for (int base = off0; base < off1; base += 64) {
        int j = base + lane;
        bool act = j < off1;
        int jc = act ? j : off0;
        int s = ssrc[jc];
        float wv = sw[jc];
        float4 elv = *reinterpret_cast<const float4*>(&el[s * HH]);
        float e0 = leaky(elv.x + erv.x) * wv;
        float e1 = leaky(elv.y + erv.y) * wv;
        float e2 = leaky(elv.z + erv.z) * wv;
        float e3 = leaky(elv.w + erv.w) * wv;
        float a0 = act ? __expf(e0 - m0) * i0 : 0.f;
        float a1 = act ? __expf(e1 - m1) * i1 : 0.f;
        float a2 = act ? __expf(e2 - m2) * i2 : 0.f;
        float a3 = act ? __expf(e3 - m3) * i3 : 0.f;
        int cnt = off1 - base; if (cnt > 64) cnt = 64;
        for (int jj = 0; jj < cnt; ++jj) {
          int sj = __shfl(s, jj, 64);
          float b0 = __shfl(a0, jj, 64);
          float b1 = __shfl(a1, jj, 64);
          float b2 = __shfl(a2, jj, 64);
          float b3 = __shfl(a3, jj, 64);
          float av = h == 0 ? b0 : h == 1 ? b1 : h == 2 ? b2 : b3;
          float2 f = *reinterpret_cast<const float2*>(&feat[(size_t)sj * CC + 2 * lane]);
          acc0 = fmaf(av, f.x, acc0);
          acc1 = fmaf(av, f.y, acc1);
        }
      }
    }
  }
  *reinterpret_cast<float2*>(&out[(size_t)n * CC + 2 * lane]) = make_float2(acc0, acc1);
}

// ---------------- launch ----------------
extern "C" void kernel_launch(void* const* d_in, const int* in_sizes, int n_in,
                              void* d_out, int out_size, void* d_ws, size_t ws_size,
                              hipStream_t stream)
{
  const float* x      = (const float*)d_in[1];
  const int*   src    = (const int*)d_in[2];
  const int*   dst    = (const int*)d_in[3];
  const float* w      = (const float*)d_in[4];
  const float* W_fc   = (const float*)d_in[5];
  const float* attn_l = (const float*)d_in[6];
  const float* attn_r = (const float*)d_in[7];
  float* out = (float*)d_out;

  int N = in_sizes[1] / IN_DIM;
  int E = in_sizes[2];

  char* p = (char*)d_ws;
  auto alloc = [&](size_t bytes) {
    char* r = p;
    p += (bytes + 255) & ~size_t(255);
    return r;
  };
  float* feat  = (float*)alloc((size_t)N * CC * 4);
  float* el    = (float*)alloc((size_t)N * HH * 4);
  float* er    = (float*)alloc((size_t)N * HH * 4);
  int*   offs  = (int*)alloc((size_t)(N + 1) * 4);
  int*   cursor= (int*)alloc((size_t)N * 4);
  int*   bsum  = (int*)alloc(256 * 4);
  int*   ssrc  = (int*)alloc((size_t)E * 4);
  float* sw    = (float*)alloc((size_t)E * 4);

  hipMemsetAsync(offs, 0, (size_t)(N + 1) * 4, stream);
  hipMemsetAsync(cursor, 0, (size_t)N * 4, stream);

  k_project<<<(N + 3) / 4, 256, 0, stream>>>(x, W_fc, attn_l, attn_r, feat, el, er, N);
  k_hist<<<(E + 255) / 256, 256, 0, stream>>>(dst, offs, E);
  int G = (N + 1023) / 1024;
  k_scan1<<<G, 256, 0, stream>>>(offs, bsum, N);
  k_scan2<<<1, 256, 0, stream>>>(bsum, G);
  k_scan3<<<(N + 255) / 256, 256, 0, stream>>>(offs, bsum, N, E);
  k_scatter<<<(E + 255) / 256, 256, 0, stream>>>(src, dst, w, offs, cursor, ssrc, sw, E);
  k_aggregate<<<(N + 3) / 4, 256, 0, stream>>>(offs, ssrc, sw, el, er, feat, out, N);
}

// Round 2
// 413.462 us; speedup vs baseline: 1.1942x; 1.1942x over previous
//
#include <hip/hip_runtime.h>
#include <math.h>

#define IN_DIM 64
#define HH 4
#define CC 128   /* HH*DD */
#define NEG_SLOPE 0.1f

__device__ __forceinline__ float leaky(float v) { return v >= 0.f ? v : NEG_SLOPE * v; }

// bf16 helpers (round-to-nearest-even), no header dependence
__device__ __forceinline__ unsigned short f2bf(float f) {
  unsigned u = __float_as_uint(f);
  unsigned r = u + 0x7FFFu + ((u >> 16) & 1u);
  return (unsigned short)(r >> 16);
}
__device__ __forceinline__ float bflo(unsigned v) { return __uint_as_float(v << 16); }
__device__ __forceinline__ float bfhi(unsigned v) { return __uint_as_float(v & 0xFFFF0000u); }

// ---------------- Kernel 1: feat(bf16) = x @ W_fc ; el/er per-head dots (fp32) ------
__global__ __launch_bounds__(256) void k_project(
    const float* __restrict__ x, const float* __restrict__ W,
    const float* __restrict__ attn_l, const float* __restrict__ attn_r,
    unsigned* __restrict__ featbf, float* __restrict__ el, float* __restrict__ er,
    int N)
{
  __shared__ float Wl[IN_DIM * CC];
  __shared__ float Al[CC];
  __shared__ float Ar[CC];
  int t = threadIdx.x;
  for (int i = t; i < IN_DIM * CC / 4; i += 256)
    reinterpret_cast<float4*>(Wl)[i] = reinterpret_cast<const float4*>(W)[i];
  if (t < CC) { Al[t] = attn_l[t]; Ar[t] = attn_r[t]; }
  __syncthreads();

  int lane = t & 63;
  int row = blockIdx.x * 4 + (t >> 6);
  if (row >= N) return;

  float xv = x[row * IN_DIM + lane];           // lane k holds x[row][k]
  float acc0 = 0.f, acc1 = 0.f;                // cols 2*lane, 2*lane+1
#pragma unroll
  for (int k = 0; k < IN_DIM; ++k) {
    float xk = __shfl(xv, k, 64);
    float2 wv = *reinterpret_cast<const float2*>(&Wl[k * CC + 2 * lane]);
    acc0 = fmaf(xk, wv.x, acc0);
    acc1 = fmaf(xk, wv.y, acc1);
  }
  featbf[row * 64 + lane] = (unsigned)f2bf(acc0) | ((unsigned)f2bf(acc1) << 16);

  int c = 2 * lane;
  float pl = acc0 * Al[c] + acc1 * Al[c + 1];
  float pr = acc0 * Ar[c] + acc1 * Ar[c + 1];
#pragma unroll
  for (int m = 8; m >= 1; m >>= 1) {           // reduce within 16-lane head group
    pl += __shfl_xor(pl, m, 64);
    pr += __shfl_xor(pr, m, 64);
  }
  if ((lane & 15) == 0) {
    int h = lane >> 4;
    el[row * HH + h] = pl;
    er[row * HH + h] = pr;
  }
}

// ---------------- CSR build ----------------
__global__ void k_hist(const int* __restrict__ dst, int* __restrict__ counts, int E) {
  int i = blockIdx.x * blockDim.x + threadIdx.x;
  if (i < E) atomicAdd(&counts[dst[i]], 1);
}

// exclusive scan, 1024 elems/block (256 thr x 4)
__global__ __launch_bounds__(256) void k_scan1(int* __restrict__ data, int* __restrict__ bsum, int N) {
  __shared__ int sh[256];
  int t = threadIdx.x;
  int base = blockIdx.x * 1024 + t * 4;
  int v0 = (base + 0 < N) ? data[base + 0] : 0;
  int v1 = (base + 1 < N) ? data[base + 1] : 0;
  int v2 = (base + 2 < N) ? data[base + 2] : 0;
  int v3 = (base + 3 < N) ? data[base + 3] : 0;
  int s1 = v0 + v1, s2 = s1 + v2, s3 = s2 + v3;
  sh[t] = s3;
  __syncthreads();
  for (int off = 1; off < 256; off <<= 1) {
    int add = (t >= off) ? sh[t - off] : 0;
    __syncthreads();
    sh[t] += add;
    __syncthreads();
  }
  int incl = sh[t];
  int e0 = incl - s3;          // exclusive base for this thread
  int e1 = e0 + v0, e2 = e1 + v1, e3 = e2 + v2;
  if (base + 0 < N) data[base + 0] = e0;
  if (base + 1 < N) data[base + 1] = e1;
  if (base + 2 < N) data[base + 2] = e2;
  if (base + 3 < N) data[base + 3] = e3;
  if (t == 255) bsum[blockIdx.x] = incl;
}

__global__ __launch_bounds__(256) void k_scan2(int* __restrict__ bsum, int G) {
  __shared__ int sh[256];
  int t = threadIdx.x;
  int v = (t < G) ? bsum[t] : 0;
  sh[t] = v;
  __syncthreads();
  for (int off = 1; off < 256; off <<= 1) {
    int add = (t >= off) ? sh[t - off] : 0;
    __syncthreads();
    sh[t] += add;
    __syncthreads();
  }
  if (t < G) bsum[t] = sh[t] - v;  // exclusive
}

__global__ void k_scan3(int* __restrict__ data, int* __restrict__ cursor,
                        const int* __restrict__ bsum, int N, int E) {
  int i = blockIdx.x * blockDim.x + threadIdx.x;
  if (i < N) {
    int v = data[i] + bsum[i >> 10];
    data[i] = v;
    cursor[i] = v;      // cursor starts at row base -> scatter atomicAdd gives abs pos
  }
  if (i == 0) data[N] = E;
}

__global__ void k_scatter(const int* __restrict__ src, const int* __restrict__ dst,
                          const float* __restrict__ w,
                          int* __restrict__ cursor, int2* __restrict__ sp, int E) {
  int i = blockIdx.x * blockDim.x + threadIdx.x;
  if (i < E) {
    int d = dst[i];
    int pos = atomicAdd(&cursor[d], 1);
    sp[pos] = make_int2(src[i], __float_as_int(w[i]));   // 8B packed payload, 1 line
  }
}

// ---------------- Kernel 3: per-node softmax + weighted gather-sum ----------------
// wave per node; FMA loop does 2 edges/iter: lanes 0-31 -> edge 2t, lanes 32-63 -> edge 2t+1
__global__ __launch_bounds__(256) void k_aggregate(
    const int* __restrict__ offs, const int2* __restrict__ sp,
    const float* __restrict__ el, const float* __restrict__ er,
    const uint2* __restrict__ featbf, float* __restrict__ out, int N)
{
  __shared__ int   s_lds[4][64];
  __shared__ float4 a_lds[4][64];

  int t = threadIdx.x;
  int lane = t & 63, wv = t >> 6;
  int n = blockIdx.x * 4 + wv;
  if (n >= N) return;

  int off0 = offs[n], off1 = offs[n + 1];
  int deg = off1 - off0;
  int half = lane >> 5;
  int l32 = lane & 31;
  int h = l32 >> 3;                // head owning cols 4*l32 .. 4*l32+3
  float4 acc = make_float4(0.f, 0.f, 0.f, 0.f);

  if (deg > 0) {
    float4 erv = *reinterpret_cast<const float4*>(&er[n * HH]);
    if (deg <= 64) {
      bool act = lane < deg;
      int2 p = sp[off0 + (act ? lane : 0)];
      int s = p.x;
      float wgt = __int_as_float(p.y);
      float4 elv = *reinterpret_cast<const float4*>(&el[s * HH]);
      float e0 = act ? leaky(elv.x + erv.x) * wgt : -INFINITY;
      float e1 = act ? leaky(elv.y + erv.y) * wgt : -INFINITY;
      float e2 = act ? leaky(elv.z + erv.z) * wgt : -INFINITY;
      float e3 = act ? leaky(elv.w + erv.w) * wgt : -INFINITY;
      float m0 = e0, m1 = e1, m2 = e2, m3 = e3;
#pragma unroll
      for (int d = 32; d >= 1; d >>= 1) {
        m0 = fmaxf(m0, __shfl_xor(m0, d, 64));
        m1 = fmaxf(m1, __shfl_xor(m1, d, 64));
        m2 = fmaxf(m2, __shfl_xor(m2, d, 64));
        m3 = fmaxf(m3, __shfl_xor(m3, d, 64));
      }
      float x0 = act ? __expf(e0 - m0) : 0.f;
      float x1 = act ? __expf(e1 - m1) : 0.f;
      float x2 = act ? __expf(e2 - m2) : 0.f;
      float x3 = act ? __expf(e3 - m3) : 0.f;
      float d0 = x0, d1 = x1, d2 = x2, d3 = x3;
#pragma unroll
      for (int d = 32; d >= 1; d >>= 1) {
        d0 += __shfl_xor(d0, d, 64);
        d1 += __shfl_xor(d1, d, 64);
        d2 += __shfl_xor(d2, d, 64);
        d3 += __shfl_xor(d3, d, 64);
      }
      float a0 = x0 * __builtin_amdgcn_rcpf(d0);
      float a1 = x1 * __builtin_amdgcn_rcpf(d1);
      float a2 = x2 * __builtin_amdgcn_rcpf(d2);
      float a3 = x3 * __builtin_amdgcn_rcpf(d3);
      s_lds[wv][lane] = s;
      a_lds[wv][lane] = make_float4(a0, a1, a2, a3);

      int npair = (deg + 1) >> 1;
      for (int tt = 0; tt < npair; ++tt) {
        int idx = 2 * tt + half;
        bool v = idx < deg;
        float a = v ? reinterpret_cast<const float*>(&a_lds[wv][idx])[h] : 0.f;
        int sj = s_lds[wv][v ? idx : 0];
        uint2 f = featbf[(size_t)sj * 32 + l32];
        acc.x = fmaf(a, bflo(f.x), acc.x);
        acc.y = fmaf(a, bfhi(f.x), acc.y);
        acc.z = fmaf(a, bflo(f.y), acc.z);
        acc.w = fmaf(a, bfhi(f.y), acc.w);
      }
    } else {
      // chunked fallback (deg > 64): 3 passes
      float m0 = -INFINITY, m1 = -INFINITY, m2 = -INFINITY, m3 = -INFINITY;
      for (int base = off0; base < off1; base += 64) {
        int j = base + lane;
        bool act = j < off1;
        int2 p = sp[act ? j : off0];
        float wgt = __int_as_float(p.y);
        float4 elv = *reinterpret_cast<const float4*>(&el[p.x * HH]);
        float e0 = act ? leaky(elv.x + erv.x) * wgt : -INFINITY;
        float e1 = act ? leaky(elv.y + erv.y) * wgt : -INFINITY;
        float e2 = act ? leaky(elv.z + erv.z) * wgt : -INFINITY;
        float e3 = act ? leaky(elv.w + erv.w) * wgt : -INFINITY;
        m0 = fmaxf(m0, e0); m1 = fmaxf(m1, e1);
        m2 = fmaxf(m2, e2); m3 = fmaxf(m3, e3);
      }
#pragma unroll
      for (int d = 32; d >= 1; d >>= 1) {
        m0 = fmaxf(m0, __shfl_xor(m0, d, 64));
        m1 = fmaxf(m1, __shfl_xor(m1, d, 64));
        m2 = fmaxf(m2, __shfl_xor(m2, d, 64));
        m3 = fmaxf(m3, __shfl_xor(m3, d, 64));
      }
      float d0 = 0.f, d1 = 0.f, d2 = 0.f, d3 = 0.f;
      for (int base = off0; base < off1; base += 64) {
        int j = base + lane;
        bool act = j < off1;
        int2 p = sp[act ? j : off0];
        float wgt = __int_as_float(p.y);
        float4 elv = *reinterpret_cast<const float4*>(&el[p.x * HH]);
        float e0 = leaky(elv.x + erv.x) * wgt;
        float e1 = leaky(elv.y + erv.y) * wgt;
        float e2 = leaky(elv.z + erv.z) * wgt;
        float e3 = leaky(elv.w + erv.w) * wgt;
        d0 += act ? __expf(e0 - m0) : 0.f;
        d1 += act ? __expf(e1 - m1) : 0.f;
        d2 += act ? __expf(e2 - m2) : 0.f;
        d3 += act ? __expf(e3 - m3) : 0.f;
      }
#pragma unroll
      for (int d = 32; d >= 1; d >>= 1) {
        d0 += __shfl_xor(d0, d, 64);
        d1 += __shfl_xor(d1, d, 64);
        d2 += __shfl_xor(d2, d, 64);
        d3 += __shfl_xor(d3, d, 64);
      }
      float i0 = __builtin_amdgcn_rcpf(d0), i1 = __builtin_amdgcn_rcpf(d1);
      float i2 = __builtin_amdgcn_rcpf(d2), i3 = __builtin_amdgcn_rcpf(d3);
      for (int base = off0; base < off1; base += 64) {
        int j = base + lane;
        bool act = j < off1;
        int2 p = sp[act ? j : off0];
        float wgt = __int_as_float(p.y);
        float4 elv = *reinterpret_cast<const float4*>(&el[p.x * HH]);
        float e0 = leaky(elv.x + erv.x) * wgt;
        float e1 = leaky(elv.y + erv.y) * wgt;
        float e2 = leaky(elv.z + erv.z) * wgt;
        float e3 = leaky(elv.w + erv.w) * wgt;
        float a0 = act ? __expf(e0 - m0) * i0 : 0.f;
        float a1 = act ? __expf(e1 - m1) * i1 : 0.f;
        float a2 = act ? __expf(e2 - m2) * i2 : 0.f;
        float a3 = act ? __expf(e3 - m3) * i3 : 0.f;
        s_lds[wv][lane] = p.x;
        a_lds[wv][lane] = make_float4(a0, a1, a2, a3);
        int cnt = off1 - base; if (cnt > 64) cnt = 64;
        int npair = (cnt + 1) >> 1;
        for (int tt = 0; tt < npair; ++tt) {
          int idx = 2 * tt + half;
          bool v = idx < cnt;
          float a = v ? reinterpret_cast<const float*>(&a_lds[wv][idx])[h] : 0.f;
          int sj = s_lds[wv][v ? idx : 0];
          uint2 f = featbf[(size_t)sj * 32 + l32];
          acc.x = fmaf(a, bflo(f.x), acc.x);
          acc.y = fmaf(a, bfhi(f.x), acc.y);
          acc.z = fmaf(a, bflo(f.y), acc.z);
          acc.w = fmaf(a, bfhi(f.y), acc.w);
        }
      }
    }
  }
  // combine the two half-wave accumulators (same cols)
  acc.x += __shfl_xor(acc.x, 32, 64);
  acc.y += __shfl_xor(acc.y, 32, 64);
  acc.z += __shfl_xor(acc.z, 32, 64);
  acc.w += __shfl_xor(acc.w, 32, 64);
  if (lane < 32)
    *reinterpret_cast<float4*>(&out[(size_t)n * CC + 4 * l32]) = acc;
}

// ---------------- launch ----------------
extern "C" void kernel_launch(void* const* d_in, const int* in_sizes, int n_in,
                              void* d_out, int out_size, void* d_ws, size_t ws_size,
                              hipStream_t stream)
{
  const float* x      = (const float*)d_in[1];
  const int*   src    = (const int*)d_in[2];
  const int*   dst    = (const int*)d_in[3];
  const float* w      = (const float*)d_in[4];
  const float* W_fc   = (const float*)d_in[5];
  const float* attn_l = (const float*)d_in[6];
  const float* attn_r = (const float*)d_in[7];
  float* out = (float*)d_out;

  int N = in_sizes[1] / IN_DIM;
  int E = in_sizes[2];

  char* p = (char*)d_ws;
  auto alloc = [&](size_t bytes) {
    char* r = p;
    p += (bytes + 255) & ~size_t(255);
    return r;
  };
  unsigned* featbf = (unsigned*)alloc((size_t)N * 64 * 4);   // bf16 x2 packed
  float* el    = (float*)alloc((size_t)N * HH * 4);
  float* er    = (float*)alloc((size_t)N * HH * 4);
  int*   offs  = (int*)alloc((size_t)(N + 1) * 4);
  int*   cursor= (int*)alloc((size_t)N * 4);
  int*   bsum  = (int*)alloc(256 * 4);
  int2*  sp    = (int2*)alloc((size_t)E * 8);

  hipMemsetAsync(offs, 0, (size_t)(N + 1) * 4, stream);

  k_project<<<(N + 3) / 4, 256, 0, stream>>>(x, W_fc, attn_l, attn_r, featbf, el, er, N);
  k_hist<<<(E + 255) / 256, 256, 0, stream>>>(dst, offs, E);
  int G = (N + 1023) / 1024;
  k_scan1<<<G, 256, 0, stream>>>(offs, bsum, N);
  k_scan2<<<1, 256, 0, stream>>>(bsum, G);
  k_scan3<<<(N + 255) / 256, 256, 0, stream>>>(offs, cursor, bsum, N, E);
  k_scatter<<<(E + 255) / 256, 256, 0, stream>>>(src, dst, w, cursor, sp, E);
  k_aggregate<<<(N + 3) / 4, 256, 0, stream>>>(offs, sp, el, er, (const uint2*)featbf, out, N);
}

// Round 3
// 288.311 us; speedup vs baseline: 1.7126x; 1.4341x over previous
//
#include <hip/hip_runtime.h>
#include <math.h>

#define IN_DIM 64
#define HH 4
#define CC 128   /* HH*DD */
#define NEG_SLOPE 0.1f

typedef __attribute__((ext_vector_type(8))) short short8;
typedef __attribute__((ext_vector_type(4))) float f32x4;

__device__ __forceinline__ float leaky(float v) { return v >= 0.f ? v : NEG_SLOPE * v; }

// bf16 helpers (round-to-nearest-even)
__device__ __forceinline__ unsigned f2bf(float f) {
  unsigned u = __float_as_uint(f);
  unsigned r = u + 0x7FFFu + ((u >> 16) & 1u);
  return r >> 16;
}
__device__ __forceinline__ float bflo(unsigned v) { return __uint_as_float(v << 16); }
__device__ __forceinline__ float bfhi(unsigned v) { return __uint_as_float(v & 0xFFFF0000u); }

// ---------------- Kernel 0: build swizzled bf16 W^T image (128 rows x 32 u32) ------
// logical: Wt[n][k] = W[k][n], bf16, pairs (k, k+1) in one u32.
// physical u32 index: n*32 + (b ^ (n&7))*4 + h   where b = k/8, h = (k%8)/2
__global__ void k_prepw(const float* __restrict__ W, unsigned* __restrict__ wt) {
  int tid = blockIdx.x * 256 + threadIdx.x;
  if (tid >= 128 * 32) return;
  int n = tid >> 5;
  int r = tid & 31;
  int b = r >> 2, h = r & 3;
  int k = b * 8 + h * 2;
  unsigned lo = f2bf(W[k * CC + n]);
  unsigned hi = f2bf(W[(k + 1) * CC + n]);
  wt[n * 32 + (b ^ (n & 7)) * 4 + h] = lo | (hi << 16);
}

// ---------------- Kernel 1: MFMA projection: feat(bf16), el/er (fp32) ----------------
// wave handles 16 nodes x 128 outcols. D = Wt_tile(A) x xT_tile(B):
//   lane: node = base + (lane&15); outcols c*16 + (lane>>4)*4 + reg
__global__ __launch_bounds__(256) void k_project(
    const float* __restrict__ x, const unsigned* __restrict__ wt,
    const float* __restrict__ attn_l, const float* __restrict__ attn_r,
    unsigned* __restrict__ featbf, float* __restrict__ el, float* __restrict__ er,
    int N)
{
  __shared__ unsigned Wlds[4096];   // 16 KB swizzled Wt bf16
  __shared__ float Al[CC], Ar[CC];
  int t = threadIdx.x;
  {
    const uint4* s = (const uint4*)wt;
    uint4* d = (uint4*)Wlds;
#pragma unroll
    for (int i = 0; i < 4; ++i) d[t + 256 * i] = s[t + 256 * i];
  }
  if (t < CC) { Al[t] = attn_l[t]; Ar[t] = attn_r[t]; }
  __syncthreads();

  int lane = t & 63;
  int l4 = lane >> 4, l16 = lane & 15;
  int node = blockIdx.x * 64 + (t >> 6) * 16 + l16;
  bool valid = node < N;
  int nrow = valid ? node : 0;

  // B fragments: x[node] k-slices, converted to bf16
  short8 bfr[2];
#pragma unroll
  for (int s = 0; s < 2; ++s) {
    const float4* xp = (const float4*)&x[(size_t)nrow * 64 + s * 32 + l4 * 8];
    float4 xa = xp[0], xb = xp[1];
    union { short8 v; unsigned u[4]; } pk;
    pk.u[0] = f2bf(xa.x) | (f2bf(xa.y) << 16);
    pk.u[1] = f2bf(xa.z) | (f2bf(xa.w) << 16);
    pk.u[2] = f2bf(xb.x) | (f2bf(xb.y) << 16);
    pk.u[3] = f2bf(xb.z) | (f2bf(xb.w) << 16);
    bfr[s] = pk.v;
  }

  f32x4 acc[8];
#pragma unroll
  for (int c = 0; c < 8; ++c) acc[c] = (f32x4){0.f, 0.f, 0.f, 0.f};

#pragma unroll
  for (int c = 0; c < 8; ++c) {
    int n0 = c * 16 + l16;          // Wt row (= out col tile row)
    int sw = n0 & 7;
#pragma unroll
    for (int s = 0; s < 2; ++s) {
      int b = s * 4 + l4;
      union { short8 v; uint4 q; } af;
      af.q = *(const uint4*)&Wlds[n0 * 32 + (b ^ sw) * 4];
      acc[c] = __builtin_amdgcn_mfma_f32_16x16x32_bf16(af.v, bfr[s], acc[c], 0, 0, 0);
    }
  }

  // featbf: u32 u holds cols (2u, 2u+1); lane's cols c*16 + l4*4 .. +3
  if (valid) {
#pragma unroll
    for (int c = 0; c < 8; ++c) {
      unsigned u0 = f2bf(acc[c][0]) | (f2bf(acc[c][1]) << 16);
      unsigned u1 = f2bf(acc[c][2]) | (f2bf(acc[c][3]) << 16);
      *(uint2*)&featbf[(size_t)node * 64 + c * 8 + l4 * 2] = make_uint2(u0, u1);
    }
  }

  // el/er: per-head dots, reduce over the 4 lane-groups sharing a node
  float pl[4], pr[4];
#pragma unroll
  for (int h = 0; h < 4; ++h) {
    float sl = 0.f, sr = 0.f;
#pragma unroll
    for (int ct = 0; ct < 2; ++ct) {
      int c = 2 * h + ct;
      int cb = c * 16 + l4 * 4;
#pragma unroll
      for (int r = 0; r < 4; ++r) {
        sl = fmaf(acc[c][r], Al[cb + r], sl);
        sr = fmaf(acc[c][r], Ar[cb + r], sr);
      }
    }
    sl += __shfl_xor(sl, 16, 64); sl += __shfl_xor(sl, 32, 64);
    sr += __shfl_xor(sr, 16, 64); sr += __shfl_xor(sr, 32, 64);
    pl[h] = sl; pr[h] = sr;
  }
  if (l4 == 0 && valid) {
    *(float4*)&el[(size_t)node * 4] = make_float4(pl[0], pl[1], pl[2], pl[3]);
    *(float4*)&er[(size_t)node * 4] = make_float4(pr[0], pr[1], pr[2], pr[3]);
  }
}

// ---------------- CSR build ----------------
__global__ void k_hist(const int* __restrict__ dst, int* __restrict__ counts, int E) {
  int i = blockIdx.x * blockDim.x + threadIdx.x;
  if (i < E) atomicAdd(&counts[dst[i]], 1);
}

__global__ __launch_bounds__(256) void k_scan1(int* __restrict__ data, int* __restrict__ bsum, int N) {
  __shared__ int sh[256];
  int t = threadIdx.x;
  int base = blockIdx.x * 1024 + t * 4;
  int v0 = (base + 0 < N) ? data[base + 0] : 0;
  int v1 = (base + 1 < N) ? data[base + 1] : 0;
  int v2 = (base + 2 < N) ? data[base + 2] : 0;
  int v3 = (base + 3 < N) ? data[base + 3] : 0;
  int s1 = v0 + v1, s2 = s1 + v2, s3 = s2 + v3;
  sh[t] = s3;
  __syncthreads();
  for (int off = 1; off < 256; off <<= 1) {
    int add = (t >= off) ? sh[t - off] : 0;
    __syncthreads();
    sh[t] += add;
    __syncthreads();
  }
  int incl = sh[t];
  int e0 = incl - s3;
  int e1 = e0 + v0, e2 = e1 + v1, e3 = e2 + v2;
  if (base + 0 < N) data[base + 0] = e0;
  if (base + 1 < N) data[base + 1] = e1;
  if (base + 2 < N) data[base + 2] = e2;
  if (base + 3 < N) data[base + 3] = e3;
  if (t == 255) bsum[blockIdx.x] = incl;
}

__global__ __launch_bounds__(256) void k_scan2(int* __restrict__ bsum, int G) {
  __shared__ int sh[256];
  int t = threadIdx.x;
  int v = (t < G) ? bsum[t] : 0;
  sh[t] = v;
  __syncthreads();
  for (int off = 1; off < 256; off <<= 1) {
    int add = (t >= off) ? sh[t - off] : 0;
    __syncthreads();
    sh[t] += add;
    __syncthreads();
  }
  if (t < G) bsum[t] = sh[t] - v;
}

__global__ void k_scan3(int* __restrict__ data, int* __restrict__ cursor,
                        const int* __restrict__ bsum, int N, int E) {
  int i = blockIdx.x * blockDim.x + threadIdx.x;
  if (i < N) {
    int v = data[i] + bsum[i >> 10];
    data[i] = v;
    cursor[i] = v;
  }
  if (i == 0) data[N] = E;
}

__global__ void k_scatter(const int* __restrict__ src, const int* __restrict__ dst,
                          const float* __restrict__ w,
                          int* __restrict__ cursor, int2* __restrict__ sp, int E) {
  int i = blockIdx.x * blockDim.x + threadIdx.x;
  if (i < E) {
    int d = dst[i];
    int pos = atomicAdd(&cursor[d], 1);
    sp[pos] = make_int2(src[i], __float_as_int(w[i]));
  }
}

// ---------------- Kernel 3: per-node softmax + weighted gather-sum ----------------
__global__ __launch_bounds__(256) void k_aggregate(
    const int* __restrict__ offs, const int2* __restrict__ sp,
    const float* __restrict__ el, const float* __restrict__ er,
    const uint2* __restrict__ featbf, float* __restrict__ out, int N)
{
  __shared__ int   s_lds[4][64];
  __shared__ float4 a_lds[4][64];

  int t = threadIdx.x;
  int lane = t & 63, wv = t >> 6;
  int n = blockIdx.x * 4 + wv;
  if (n >= N) return;

  int off0 = offs[n], off1 = offs[n + 1];
  int deg = off1 - off0;
  int half = lane >> 5;
  int l32 = lane & 31;
  int h = l32 >> 3;
  float4 acc = make_float4(0.f, 0.f, 0.f, 0.f);

  if (deg > 0) {
    float4 erv = *reinterpret_cast<const float4*>(&er[n * HH]);
    if (deg <= 64) {
      bool act = lane < deg;
      int2 p = sp[off0 + (act ? lane : 0)];
      int s = p.x;
      float wgt = __int_as_float(p.y);
      float4 elv = *reinterpret_cast<const float4*>(&el[s * HH]);
      float e0 = act ? leaky(elv.x + erv.x) * wgt : -INFINITY;
      float e1 = act ? leaky(elv.y + erv.y) * wgt : -INFINITY;
      float e2 = act ? leaky(elv.z + erv.z) * wgt : -INFINITY;
      float e3 = act ? leaky(elv.w + erv.w) * wgt : -INFINITY;
      float m0 = e0, m1 = e1, m2 = e2, m3 = e3;
#pragma unroll
      for (int d = 32; d >= 1; d >>= 1) {
        m0 = fmaxf(m0, __shfl_xor(m0, d, 64));
        m1 = fmaxf(m1, __shfl_xor(m1, d, 64));
        m2 = fmaxf(m2, __shfl_xor(m2, d, 64));
        m3 = fmaxf(m3, __shfl_xor(m3, d, 64));
      }
      float x0 = act ? __expf(e0 - m0) : 0.f;
      float x1 = act ? __expf(e1 - m1) : 0.f;
      float x2 = act ? __expf(e2 - m2) : 0.f;
      float x3 = act ? __expf(e3 - m3) : 0.f;
      float d0 = x0, d1 = x1, d2 = x2, d3 = x3;
#pragma unroll
      for (int d = 32; d >= 1; d >>= 1) {
        d0 += __shfl_xor(d0, d, 64);
        d1 += __shfl_xor(d1, d, 64);
        d2 += __shfl_xor(d2, d, 64);
        d3 += __shfl_xor(d3, d, 64);
      }
      float a0 = x0 * __builtin_amdgcn_rcpf(d0);
      float a1 = x1 * __builtin_amdgcn_rcpf(d1);
      float a2 = x2 * __builtin_amdgcn_rcpf(d2);
      float a3 = x3 * __builtin_amdgcn_rcpf(d3);
      s_lds[wv][lane] = s;
      a_lds[wv][lane] = make_float4(a0, a1, a2, a3);

      int npair = (deg + 1) >> 1;
      for (int tt = 0; tt < npair; ++tt) {
        int idx = 2 * tt + half;
        bool v = idx < deg;
        float a = v ? reinterpret_cast<const float*>(&a_lds[wv][idx])[h] : 0.f;
        int sj = s_lds[wv][v ? idx : 0];
        uint2 f = featbf[(size_t)sj * 32 + l32];
        acc.x = fmaf(a, bflo(f.x), acc.x);
        acc.y = fmaf(a, bfhi(f.x), acc.y);
        acc.z = fmaf(a, bflo(f.y), acc.z);
        acc.w = fmaf(a, bfhi(f.y), acc.w);
      }
    } else {
      float m0 = -INFINITY, m1 = -INFINITY, m2 = -INFINITY, m3 = -INFINITY;
      for (int base = off0; base < off1; base += 64) {
        int j = base + lane;
        bool act = j < off1;
        int2 p = sp[act ? j : off0];
        float wgt = __int_as_float(p.y);
        float4 elv = *reinterpret_cast<const float4*>(&el[p.x * HH]);
        float e0 = act ? leaky(elv.x + erv.x) * wgt : -INFINITY;
        float e1 = act ? leaky(elv.y + erv.y) * wgt : -INFINITY;
        float e2 = act ? leaky(elv.z + erv.z) * wgt : -INFINITY;
        float e3 = act ? leaky(elv.w + erv.w) * wgt : -INFINITY;
        m0 = fmaxf(m0, e0); m1 = fmaxf(m1, e1);
        m2 = fmaxf(m2, e2); m3 = fmaxf(m3, e3);
      }
#pragma unroll
      for (int d = 32; d >= 1; d >>= 1) {
        m0 = fmaxf(m0, __shfl_xor(m0, d, 64));
        m1 = fmaxf(m1, __shfl_xor(m1, d, 64));
        m2 = fmaxf(m2, __shfl_xor(m2, d, 64));
        m3 = fmaxf(m3, __shfl_xor(m3, d, 64));
      }
      float d0 = 0.f, d1 = 0.f, d2 = 0.f, d3 = 0.f;
      for (int base = off0; base < off1; base += 64) {
        int j = base + lane;
        bool act = j < off1;
        int2 p = sp[act ? j : off0];
        float wgt = __int_as_float(p.y);
        float4 elv = *reinterpret_cast<const float4*>(&el[p.x * HH]);
        float e0 = leaky(elv.x + erv.x) * wgt;
        float e1 = leaky(elv.y + erv.y) * wgt;
        float e2 = leaky(elv.z + erv.z) * wgt;
        float e3 = leaky(elv.w + erv.w) * wgt;
        d0 += act ? __expf(e0 - m0) : 0.f;
        d1 += act ? __expf(e1 - m1) : 0.f;
        d2 += act ? __expf(e2 - m2) : 0.f;
        d3 += act ? __expf(e3 - m3) : 0.f;
      }
#pragma unroll
      for (int d = 32; d >= 1; d >>= 1) {
        d0 += __shfl_xor(d0, d, 64);
        d1 += __shfl_xor(d1, d, 64);
        d2 += __shfl_xor(d2, d, 64);
        d3 += __shfl_xor(d3, d, 64);
      }
      float i0 = __builtin_amdgcn_rcpf(d0), i1 = __builtin_amdgcn_rcpf(d1);
      float i2 = __builtin_amdgcn_rcpf(d2), i3 = __builtin_amdgcn_rcpf(d3);
      for (int base = off0; base < off1; base += 64) {
        int j = base + lane;
        bool act = j < off1;
        int2 p = sp[act ? j : off0];
        float wgt = __int_as_float(p.y);
        float4 elv = *reinterpret_cast<const float4*>(&el[p.x * HH]);
        float e0 = leaky(elv.x + erv.x) * wgt;
        float e1 = leaky(elv.y + erv.y) * wgt;
        float e2 = leaky(elv.z + erv.z) * wgt;
        float e3 = leaky(elv.w + erv.w) * wgt;
        float a0 = act ? __expf(e0 - m0) * i0 : 0.f;
        float a1 = act ? __expf(e1 - m1) * i1 : 0.f;
        float a2 = act ? __expf(e2 - m2) * i2 : 0.f;
        float a3 = act ? __expf(e3 - m3) * i3 : 0.f;
        s_lds[wv][lane] = p.x;
        a_lds[wv][lane] = make_float4(a0, a1, a2, a3);
        int cnt = off1 - base; if (cnt > 64) cnt = 64;
        int npair = (cnt + 1) >> 1;
        for (int tt = 0; tt < npair; ++tt) {
          int idx = 2 * tt + half;
          bool v = idx < cnt;
          float a = v ? reinterpret_cast<const float*>(&a_lds[wv][idx])[h] : 0.f;
          int sj = s_lds[wv][v ? idx : 0];
          uint2 f = featbf[(size_t)sj * 32 + l32];
          acc.x = fmaf(a, bflo(f.x), acc.x);
          acc.y = fmaf(a, bfhi(f.x), acc.y);
          acc.z = fmaf(a, bflo(f.y), acc.z);
          acc.w = fmaf(a, bfhi(f.y), acc.w);
        }
      }
    }
  }
  acc.x += __shfl_xor(acc.x, 32, 64);
  acc.y += __shfl_xor(acc.y, 32, 64);
  acc.z += __shfl_xor(acc.z, 32, 64);
  acc.w += __shfl_xor(acc.w, 32, 64);
  if (lane < 32)
    *reinterpret_cast<float4*>(&out[(size_t)n * CC + 4 * l32]) = acc;
}

// ---------------- launch ----------------
extern "C" void kernel_launch(void* const* d_in, const int* in_sizes, int n_in,
                              void* d_out, int out_size, void* d_ws, size_t ws_size,
                              hipStream_t stream)
{
  const float* x      = (const float*)d_in[1];
  const int*   src    = (const int*)d_in[2];
  const int*   dst    = (const int*)d_in[3];
  const float* w      = (const float*)d_in[4];
  const float* W_fc   = (const float*)d_in[5];
  const float* attn_l = (const float*)d_in[6];
  const float* attn_r = (const float*)d_in[7];
  float* out = (float*)d_out;

  int N = in_sizes[1] / IN_DIM;
  int E = in_sizes[2];

  char* p = (char*)d_ws;
  auto alloc = [&](size_t bytes) {
    char* r = p;
    p += (bytes + 255) & ~size_t(255);
    return r;
  };
  unsigned* featbf = (unsigned*)alloc((size_t)N * 64 * 4);   // bf16 x2 packed
  float* el    = (float*)alloc((size_t)N * HH * 4);
  float* er    = (float*)alloc((size_t)N * HH * 4);
  int*   offs  = (int*)alloc((size_t)(N + 1) * 4);
  int*   cursor= (int*)alloc((size_t)N * 4);
  int*   bsum  = (int*)alloc(256 * 4);
  unsigned* wtswz = (unsigned*)alloc(4096 * 4);              // swizzled bf16 W^T
  int2*  sp    = (int2*)alloc((size_t)E * 8);

  hipMemsetAsync(offs, 0, (size_t)(N + 1) * 4, stream);

  k_prepw<<<16, 256, 0, stream>>>(W_fc, wtswz);
  k_project<<<(N + 63) / 64, 256, 0, stream>>>(x, wtswz, attn_l, attn_r, featbf, el, er, N);
  k_hist<<<(E + 255) / 256, 256, 0, stream>>>(dst, offs, E);
  int G = (N + 1023) / 1024;
  k_scan1<<<G, 256, 0, stream>>>(offs, bsum, N);
  k_scan2<<<1, 256, 0, stream>>>(bsum, G);
  k_scan3<<<(N + 255) / 256, 256, 0, stream>>>(offs, cursor, bsum, N, E);
  k_scatter<<<(E + 255) / 256, 256, 0, stream>>>(src, dst, w, cursor, sp, E);
  k_aggregate<<<(N + 3) / 4, 256, 0, stream>>>(offs, sp, el, er, (const uint2*)featbf, out, N);
}

// Round 4
// 152.456 us; speedup vs baseline: 3.2386x; 1.8911x over previous
//
#include <hip/hip_runtime.h>
#include <math.h>

#define IN_DIM 64
#define HH 4
#define CC 128   /* HH*DD */
#define NEG_SLOPE 0.1f

typedef __attribute__((ext_vector_type(8))) short short8;
typedef __attribute__((ext_vector_type(4))) float f32x4;

__device__ __forceinline__ float leaky(float v) { return v >= 0.f ? v : NEG_SLOPE * v; }

// bf16 helpers (round-to-nearest-even)
__device__ __forceinline__ unsigned f2bf(float f) {
  unsigned u = __float_as_uint(f);
  unsigned r = u + 0x7FFFu + ((u >> 16) & 1u);
  return r >> 16;
}
__device__ __forceinline__ float bflo(unsigned v) { return __uint_as_float(v << 16); }
__device__ __forceinline__ float bfhi(unsigned v) { return __uint_as_float(v & 0xFFFF0000u); }

// ---------------- Kernel 0: build swizzled bf16 W^T image (128 rows x 32 u32) ------
__global__ void k_prepw(const float* __restrict__ W, unsigned* __restrict__ wt) {
  int tid = blockIdx.x * 256 + threadIdx.x;
  if (tid >= 128 * 32) return;
  int n = tid >> 5;
  int r = tid & 31;
  int b = r >> 2, h = r & 3;
  int k = b * 8 + h * 2;
  unsigned lo = f2bf(W[k * CC + n]);
  unsigned hi = f2bf(W[(k + 1) * CC + n]);
  wt[n * 32 + (b ^ (n & 7)) * 4 + h] = lo | (hi << 16);
}

// ---------------- Kernel 1: MFMA projection: feat(bf16), el/er (fp32) ----------------
__global__ __launch_bounds__(256) void k_project(
    const float* __restrict__ x, const unsigned* __restrict__ wt,
    const float* __restrict__ attn_l, const float* __restrict__ attn_r,
    unsigned* __restrict__ featbf, float* __restrict__ el, float* __restrict__ er,
    int N)
{
  __shared__ unsigned Wlds[4096];   // 16 KB swizzled Wt bf16
  __shared__ float Al[CC], Ar[CC];
  int t = threadIdx.x;
  {
    const uint4* s = (const uint4*)wt;
    uint4* d = (uint4*)Wlds;
#pragma unroll
    for (int i = 0; i < 4; ++i) d[t + 256 * i] = s[t + 256 * i];
  }
  if (t < CC) { Al[t] = attn_l[t]; Ar[t] = attn_r[t]; }
  __syncthreads();

  int lane = t & 63;
  int l4 = lane >> 4, l16 = lane & 15;
  int node = blockIdx.x * 64 + (t >> 6) * 16 + l16;
  bool valid = node < N;
  int nrow = valid ? node : 0;

  short8 bfr[2];
#pragma unroll
  for (int s = 0; s < 2; ++s) {
    const float4* xp = (const float4*)&x[(size_t)nrow * 64 + s * 32 + l4 * 8];
    float4 xa = xp[0], xb = xp[1];
    union { short8 v; unsigned u[4]; } pk;
    pk.u[0] = f2bf(xa.x) | (f2bf(xa.y) << 16);
    pk.u[1] = f2bf(xa.z) | (f2bf(xa.w) << 16);
    pk.u[2] = f2bf(xb.x) | (f2bf(xb.y) << 16);
    pk.u[3] = f2bf(xb.z) | (f2bf(xb.w) << 16);
    bfr[s] = pk.v;
  }

  f32x4 acc[8];
#pragma unroll
  for (int c = 0; c < 8; ++c) acc[c] = (f32x4){0.f, 0.f, 0.f, 0.f};

#pragma unroll
  for (int c = 0; c < 8; ++c) {
    int n0 = c * 16 + l16;
    int sw = n0 & 7;
#pragma unroll
    for (int s = 0; s < 2; ++s) {
      int b = s * 4 + l4;
      union { short8 v; uint4 q; } af;
      af.q = *(const uint4*)&Wlds[n0 * 32 + (b ^ sw) * 4];
      acc[c] = __builtin_amdgcn_mfma_f32_16x16x32_bf16(af.v, bfr[s], acc[c], 0, 0, 0);
    }
  }

  if (valid) {
#pragma unroll
    for (int c = 0; c < 8; ++c) {
      unsigned u0 = f2bf(acc[c][0]) | (f2bf(acc[c][1]) << 16);
      unsigned u1 = f2bf(acc[c][2]) | (f2bf(acc[c][3]) << 16);
      *(uint2*)&featbf[(size_t)node * 64 + c * 8 + l4 * 2] = make_uint2(u0, u1);
    }
  }

  float pl[4], pr[4];
#pragma unroll
  for (int h = 0; h < 4; ++h) {
    float sl = 0.f, sr = 0.f;
#pragma unroll
    for (int ct = 0; ct < 2; ++ct) {
      int c = 2 * h + ct;
      int cb = c * 16 + l4 * 4;
#pragma unroll
      for (int r = 0; r < 4; ++r) {
        sl = fmaf(acc[c][r], Al[cb + r], sl);
        sr = fmaf(acc[c][r], Ar[cb + r], sr);
      }
    }
    sl += __shfl_xor(sl, 16, 64); sl += __shfl_xor(sl, 32, 64);
    sr += __shfl_xor(sr, 16, 64); sr += __shfl_xor(sr, 32, 64);
    pl[h] = sl; pr[h] = sr;
  }
  if (l4 == 0 && valid) {
    *(float4*)&el[(size_t)node * 4] = make_float4(pl[0], pl[1], pl[2], pl[3]);
    *(float4*)&er[(size_t)node * 4] = make_float4(pr[0], pr[1], pr[2], pr[3]);
  }
}

// ---------------- counting-sort CSR build (bucket = dst >> 8) ----------------
__global__ __launch_bounds__(256) void k_bhist(const int* __restrict__ dst,
                                               int* __restrict__ bcnt, int E, int NB) {
  __shared__ int lh[512];
  for (int i = threadIdx.x; i < NB; i += 256) lh[i] = 0;
  __syncthreads();
  int stride = gridDim.x * 256;
  for (int i = blockIdx.x * 256 + threadIdx.x; i < E; i += stride)
    atomicAdd(&lh[dst[i] >> 8], 1);
  __syncthreads();
  for (int i = threadIdx.x; i < NB; i += 256) {
    int c = lh[i];
    if (c) atomicAdd(&bcnt[i], c);
  }
}

__global__ __launch_bounds__(512) void k_bscan(const int* __restrict__ bcnt,
                                               int* __restrict__ gbase,
                                               int* __restrict__ gcursor, int NB) {
  __shared__ int sh[512];
  int t = threadIdx.x;
  int v = (t < NB) ? bcnt[t] : 0;
  sh[t] = v;
  __syncthreads();
  for (int off = 1; off < 512; off <<= 1) {
    int a = (t >= off) ? sh[t - off] : 0;
    __syncthreads();
    sh[t] += a;
    __syncthreads();
  }
  if (t < NB) {
    int e = sh[t] - v;
    gbase[t] = e;
    gcursor[t] = e;
  }
}

// bin 8192 edges/block into buckets; payload = (src | dst_local<<20, w)
__global__ __launch_bounds__(512) void k_binA(const int* __restrict__ src,
                                              const int* __restrict__ dst,
                                              const float* __restrict__ w,
                                              int* __restrict__ gcursor,
                                              uint2* __restrict__ bkt, int E, int NB) {
  __shared__ int lh[512];
  __shared__ int lbase[512];
  int t = threadIdx.x;
  for (int i = t; i < NB; i += 512) lh[i] = 0;
  __syncthreads();
  long eb = (long)blockIdx.x * 8192;
  int b[16]; int r[16]; unsigned px[16]; unsigned pw[16];
#pragma unroll
  for (int i = 0; i < 16; ++i) {
    long e = eb + t + i * 512;
    bool v = e < E;
    int d = v ? dst[e] : 0;
    b[i] = d >> 8;
    px[i] = v ? ((unsigned)src[e] | ((unsigned)(d & 255) << 20)) : 0u;
    pw[i] = v ? ((const unsigned*)w)[e] : 0u;
    r[i] = v ? atomicAdd(&lh[b[i]], 1) : -1;
  }
  __syncthreads();
  for (int i = t; i < NB; i += 512) {
    int c = lh[i];
    lbase[i] = c ? atomicAdd(&gcursor[i], c) : 0;
  }
  __syncthreads();
#pragma unroll
  for (int i = 0; i < 16; ++i)
    if (r[i] >= 0) bkt[lbase[b[i]] + r[i]] = make_uint2(px[i], pw[i]);
}

// per-bucket fine scatter: LDS node-hist -> scan -> offs + sp
__global__ __launch_bounds__(256) void k_binB(const uint2* __restrict__ bkt,
                                              const int* __restrict__ bcnt,
                                              const int* __restrict__ gbase,
                                              int* __restrict__ offs,
                                              int2* __restrict__ sp,
                                              int N, int E, int NB) {
  __shared__ int lh[256], sc[256], lcur[256];
  int b = blockIdx.x;
  int t = threadIdx.x;
  int base_b = gbase[b];
  int cnt_b = bcnt[b];
  lh[t] = 0;
  __syncthreads();
  for (int e = t; e < cnt_b; e += 256) {
    uint2 p = bkt[base_b + e];
    atomicAdd(&lh[(p.x >> 20) & 255], 1);
  }
  __syncthreads();
  int v = lh[t];
  sc[t] = v;
  __syncthreads();
  for (int off = 1; off < 256; off <<= 1) {
    int a = (t >= off) ? sc[t - off] : 0;
    __syncthreads();
    sc[t] += a;
    __syncthreads();
  }
  int excl = sc[t] - v;
  lcur[t] = excl;
  int n0 = b << 8;
  if (n0 + t < N) offs[n0 + t] = base_b + excl;
  if (b == NB - 1 && t == 0) offs[N] = E;
  __syncthreads();
  for (int e = t; e < cnt_b; e += 256) {
    uint2 p = bkt[base_b + e];
    int d = (p.x >> 20) & 255;
    int pos = atomicAdd(&lcur[d], 1);
    sp[base_b + pos] = make_int2((int)(p.x & 0xFFFFFu), (int)p.y);
  }
}

// ---------------- Kernel 3: per-node softmax + weighted gather-sum ----------------
__global__ __launch_bounds__(256) void k_aggregate(
    const int* __restrict__ offs, const int2* __restrict__ sp,
    const float* __restrict__ el, const float* __restrict__ er,
    const uint2* __restrict__ featbf, float* __restrict__ out, int N)
{
  __shared__ int   s_lds[4][64];
  __shared__ float4 a_lds[4][64];

  int t = threadIdx.x;
  int lane = t & 63, wv = t >> 6;
  int n = blockIdx.x * 4 + wv;
  if (n >= N) return;

  int off0 = offs[n], off1 = offs[n + 1];
  int deg = off1 - off0;
  int half = lane >> 5;
  int l32 = lane & 31;
  int h = l32 >> 3;
  float4 acc = make_float4(0.f, 0.f, 0.f, 0.f);

  if (deg > 0) {
    float4 erv = *reinterpret_cast<const float4*>(&er[n * HH]);
    if (deg <= 64) {
      bool act = lane < deg;
      int2 p = sp[off0 + (act ? lane : 0)];
      int s = p.x;
      float wgt = __int_as_float(p.y);
      float4 elv = *reinterpret_cast<const float4*>(&el[s * HH]);
      float e0 = act ? leaky(elv.x + erv.x) * wgt : -INFINITY;
      float e1 = act ? leaky(elv.y + erv.y) * wgt : -INFINITY;
      float e2 = act ? leaky(elv.z + erv.z) * wgt : -INFINITY;
      float e3 = act ? leaky(elv.w + erv.w) * wgt : -INFINITY;
      float m0 = e0, m1 = e1, m2 = e2, m3 = e3;
#pragma unroll
      for (int d = 32; d >= 1; d >>= 1) {
        m0 = fmaxf(m0, __shfl_xor(m0, d, 64));
        m1 = fmaxf(m1, __shfl_xor(m1, d, 64));
        m2 = fmaxf(m2, __shfl_xor(m2, d, 64));
        m3 = fmaxf(m3, __shfl_xor(m3, d, 64));
      }
      float x0 = act ? __expf(e0 - m0) : 0.f;
      float x1 = act ? __expf(e1 - m1) : 0.f;
      float x2 = act ? __expf(e2 - m2) : 0.f;
      float x3 = act ? __expf(e3 - m3) : 0.f;
      float d0 = x0, d1 = x1, d2 = x2, d3 = x3;
#pragma unroll
      for (int d = 32; d >= 1; d >>= 1) {
        d0 += __shfl_xor(d0, d, 64);
        d1 += __shfl_xor(d1, d, 64);
        d2 += __shfl_xor(d2, d, 64);
        d3 += __shfl_xor(d3, d, 64);
      }
      float a0 = x0 * __builtin_amdgcn_rcpf(d0);
      float a1 = x1 * __builtin_amdgcn_rcpf(d1);
      float a2 = x2 * __builtin_amdgcn_rcpf(d2);
      float a3 = x3 * __builtin_amdgcn_rcpf(d3);
      s_lds[wv][lane] = s;
      a_lds[wv][lane] = make_float4(a0, a1, a2, a3);

      int npair = (deg + 1) >> 1;
      for (int tt = 0; tt < npair; ++tt) {
        int idx = 2 * tt + half;
        bool vv = idx < deg;
        float a = vv ? reinterpret_cast<const float*>(&a_lds[wv][idx])[h] : 0.f;
        int sj = s_lds[wv][vv ? idx : 0];
        uint2 f = featbf[(size_t)sj * 32 + l32];
        acc.x = fmaf(a, bflo(f.x), acc.x);
        acc.y = fmaf(a, bfhi(f.x), acc.y);
        acc.z = fmaf(a, bflo(f.y), acc.z);
        acc.w = fmaf(a, bfhi(f.y), acc.w);
      }
    } else {
      float m0 = -INFINITY, m1 = -INFINITY, m2 = -INFINITY, m3 = -INFINITY;
      for (int base = off0; base < off1; base += 64) {
        int j = base + lane;
        bool act = j < off1;
        int2 p = sp[act ? j : off0];
        float wgt = __int_as_float(p.y);
        float4 elv = *reinterpret_cast<const float4*>(&el[p.x * HH]);
        float e0 = act ? leaky(elv.x + erv.x) * wgt : -INFINITY;
        float e1 = act ? leaky(elv.y + erv.y) * wgt : -INFINITY;
        float e2 = act ? leaky(elv.z + erv.z) * wgt : -INFINITY;
        float e3 = act ? leaky(elv.w + erv.w) * wgt : -INFINITY;
        m0 = fmaxf(m0, e0); m1 = fmaxf(m1, e1);
        m2 = fmaxf(m2, e2); m3 = fmaxf(m3, e3);
      }
#pragma unroll
      for (int d = 32; d >= 1; d >>= 1) {
        m0 = fmaxf(m0, __shfl_xor(m0, d, 64));
        m1 = fmaxf(m1, __shfl_xor(m1, d, 64));
        m2 = fmaxf(m2, __shfl_xor(m2, d, 64));
        m3 = fmaxf(m3, __shfl_xor(m3, d, 64));
      }
      float d0 = 0.f, d1 = 0.f, d2 = 0.f, d3 = 0.f;
      for (int base = off0; base < off1; base += 64) {
        int j = base + lane;
        bool act = j < off1;
        int2 p = sp[act ? j : off0];
        float wgt = __int_as_float(p.y);
        float4 elv = *reinterpret_cast<const float4*>(&el[p.x * HH]);
        float e0 = leaky(elv.x + erv.x) * wgt;
        float e1 = leaky(elv.y + erv.y) * wgt;
        float e2 = leaky(elv.z + erv.z) * wgt;
        float e3 = leaky(elv.w + erv.w) * wgt;
        d0 += act ? __expf(e0 - m0) : 0.f;
        d1 += act ? __expf(e1 - m1) : 0.f;
        d2 += act ? __expf(e2 - m2) : 0.f;
        d3 += act ? __expf(e3 - m3) : 0.f;
      }
#pragma unroll
      for (int d = 32; d >= 1; d >>= 1) {
        d0 += __shfl_xor(d0, d, 64);
        d1 += __shfl_xor(d1, d, 64);
        d2 += __shfl_xor(d2, d, 64);
        d3 += __shfl_xor(d3, d, 64);
      }
      float i0 = __builtin_amdgcn_rcpf(d0), i1 = __builtin_amdgcn_rcpf(d1);
      float i2 = __builtin_amdgcn_rcpf(d2), i3 = __builtin_amdgcn_rcpf(d3);
      for (int base = off0; base < off1; base += 64) {
        int j = base + lane;
        bool act = j < off1;
        int2 p = sp[act ? j : off0];
        float wgt = __int_as_float(p.y);
        float4 elv = *reinterpret_cast<const float4*>(&el[p.x * HH]);
        float e0 = leaky(elv.x + erv.x) * wgt;
        float e1 = leaky(elv.y + erv.y) * wgt;
        float e2 = leaky(elv.z + erv.z) * wgt;
        float e3 = leaky(elv.w + erv.w) * wgt;
        float a0 = act ? __expf(e0 - m0) * i0 : 0.f;
        float a1 = act ? __expf(e1 - m1) * i1 : 0.f;
        float a2 = act ? __expf(e2 - m2) * i2 : 0.f;
        float a3 = act ? __expf(e3 - m3) * i3 : 0.f;
        s_lds[wv][lane] = p.x;
        a_lds[wv][lane] = make_float4(a0, a1, a2, a3);
        int cnt = off1 - base; if (cnt > 64) cnt = 64;
        int npair = (cnt + 1) >> 1;
        for (int tt = 0; tt < npair; ++tt) {
          int idx = 2 * tt + half;
          bool vv = idx < cnt;
          float a = vv ? reinterpret_cast<const float*>(&a_lds[wv][idx])[h] : 0.f;
          int sj = s_lds[wv][vv ? idx : 0];
          uint2 f = featbf[(size_t)sj * 32 + l32];
          acc.x = fmaf(a, bflo(f.x), acc.x);
          acc.y = fmaf(a, bfhi(f.x), acc.y);
          acc.z = fmaf(a, bflo(f.y), acc.z);
          acc.w = fmaf(a, bfhi(f.y), acc.w);
        }
      }
    }
  }
  acc.x += __shfl_xor(acc.x, 32, 64);
  acc.y += __shfl_xor(acc.y, 32, 64);
  acc.z += __shfl_xor(acc.z, 32, 64);
  acc.w += __shfl_xor(acc.w, 32, 64);
  if (lane < 32)
    *reinterpret_cast<float4*>(&out[(size_t)n * CC + 4 * l32]) = acc;
}

// ---------------- launch ----------------
extern "C" void kernel_launch(void* const* d_in, const int* in_sizes, int n_in,
                              void* d_out, int out_size, void* d_ws, size_t ws_size,
                              hipStream_t stream)
{
  const float* x      = (const float*)d_in[1];
  const int*   src    = (const int*)d_in[2];
  const int*   dst    = (const int*)d_in[3];
  const float* w      = (const float*)d_in[4];
  const float* W_fc   = (const float*)d_in[5];
  const float* attn_l = (const float*)d_in[6];
  const float* attn_r = (const float*)d_in[7];
  float* out = (float*)d_out;

  int N = in_sizes[1] / IN_DIM;
  int E = in_sizes[2];
  int NB = (N + 255) / 256;   // nodes/bucket = 256; NB must be <= 512

  char* p = (char*)d_ws;
  auto alloc = [&](size_t bytes) {
    char* r = p;
    p += (bytes + 255) & ~size_t(255);
    return r;
  };
  unsigned* featbf = (unsigned*)alloc((size_t)N * 64 * 4);   // bf16 x2 packed
  float* el    = (float*)alloc((size_t)N * HH * 4);
  float* er    = (float*)alloc((size_t)N * HH * 4);
  int*   offs  = (int*)alloc((size_t)(N + 1) * 4);
  int*   bcnt  = (int*)alloc(512 * 4);
  int*   gbase = (int*)alloc(512 * 4);
  int*   gcur  = (int*)alloc(512 * 4);
  unsigned* wtswz = (unsigned*)alloc(4096 * 4);
  uint2* bkt   = (uint2*)alloc((size_t)E * 8);
  int2*  sp    = (int2*)alloc((size_t)E * 8);

  hipMemsetAsync(bcnt, 0, 512 * 4, stream);

  k_prepw<<<16, 256, 0, stream>>>(W_fc, wtswz);
  k_project<<<(N + 63) / 64, 256, 0, stream>>>(x, wtswz, attn_l, attn_r, featbf, el, er, N);
  k_bhist<<<256, 256, 0, stream>>>(dst, bcnt, E, NB);
  k_bscan<<<1, 512, 0, stream>>>(bcnt, gbase, gcur, NB);
  k_binA<<<(E + 8191) / 8192, 512, 0, stream>>>(src, dst, w, gcur, bkt, E, NB);
  k_binB<<<NB, 256, 0, stream>>>(bkt, bcnt, gbase, offs, sp, N, E, NB);
  k_aggregate<<<(N + 3) / 4, 256, 0, stream>>>(offs, sp, el, er, (const uint2*)featbf, out, N);
}